// Round 3
// baseline (197.512 us; speedup 1.0000x reference)
//
#include <hip/hip_runtime.h>
#include <cstdint>

typedef float floatx4 __attribute__((ext_vector_type(4)));
typedef _Float16 half8 __attribute__((ext_vector_type(8)));
typedef _Float16 half4v __attribute__((ext_vector_type(4)));

#define D_DIM 256
#define HW 1024
#define K_CODES 1024
#define NPIX 32768          // B*H*W
#define NELEM 8388608       // B*D*H*W

// output layout (floats): [quantized 8388608][q_loss][e_loss][vq_loss][idx 32768]
#define OFF_QLOSS 8388608
#define OFF_ELOSS 8388609
#define OFF_VQ    8388610
#define OFF_IDX   8388611

// ws layout (bytes) — total ~0.94 MB
#define WS_IDX     0         // int * 32768 = 131072 (packed: idx | (flagpos+1)<<10)
#define WS_C2      131072    // float * 1024 = 4096
#define WS_CNT     135168    // int cnt, int done (+pad) = 64
#define WS_PART    135232    // double * 1024 = 8192
#define WS_FLAGPX  143424    // (unused, kept for layout stability)
#define WS_FLAGTOP 176192    // floatx4 * 2 * 8192 = 262144
#define WS_CBS     438336    // swizzled fp16 codebook = 524288
#define FLAG_CAP   8192

// ref fp32 window 6.1e-5 + fp16 GEMM err ~6e-5, with slack (round-4-proven value)
#define MARGIN 2.5e-4f

// ---- numpy pairwise sum emulation for sum(v*v) over 256 elements ----
__device__ __forceinline__ float np_pairwise_sq_256(const float* __restrict__ a, int stride) {
    float half[2];
#pragma unroll
    for (int h = 0; h < 2; ++h) {
        const float* p = a + (size_t)(h * 128) * stride;
        float r[8];
#pragma unroll
        for (int j = 0; j < 8; ++j) { float t = p[(size_t)j * stride]; r[j] = __fmul_rn(t, t); }
        for (int i = 8; i < 128; i += 8)
#pragma unroll
            for (int j = 0; j < 8; ++j) {
                float t = p[(size_t)(i + j) * stride];
                r[j] = __fadd_rn(r[j], __fmul_rn(t, t));
            }
        half[h] = __fadd_rn(__fadd_rn(__fadd_rn(r[0], r[1]), __fadd_rn(r[2], r[3])),
                            __fadd_rn(__fadd_rn(r[4], r[5]), __fadd_rn(r[6], r[7])));
    }
    return __fadd_rn(half[0], half[1]);
}

// ---------------- kernel 0: prep ----------------
// blocks 0..255: swizzle codebook into MFMA-fragment order (scaled x1024).
// blocks 256..259: c2 (numpy-pairwise exact); b==256,t==0 zeroes cnt+done.
__global__ __launch_bounds__(256) void prep_kernel(const float* __restrict__ cb,
                                                   _Float16* __restrict__ cbs,
                                                   float* __restrict__ c2,
                                                   int* __restrict__ cnt) {
    int b = blockIdx.x;
    if (b < 256) {
        int idx = b * 256 + threadIdx.x;   // (code, d-quad)
        int c = idx >> 6;
        int d = (idx & 63) * 4;
        int s = d >> 5, q = (d >> 3) & 3, j0 = d & 7;
        int half = c >> 9, ch = (c >> 4) & 31, l15 = c & 15;
        int lane = q * 16 + l15;
        size_t o = ((((size_t)(half * 32 + ch) * 8 + s) * 64 + lane) * 8 + j0);
        floatx4 v = *(const floatx4*)(cb + (size_t)c * D_DIM + d);
        half4v h;
#pragma unroll
        for (int j = 0; j < 4; ++j) h[j] = (_Float16)(v[j] * 1024.0f);  // exact pow2
        *(half4v*)(cbs + o) = h;
    } else {
        if (b == 256 && threadIdx.x == 0) { cnt[0] = 0; cnt[1] = 0; }
        int k = (b - 256) * 256 + threadIdx.x;
        c2[k] = np_pairwise_sq_256(cb + (size_t)k * D_DIM, 1);
    }
}

// top-4 insert, no index tiebreak (ties land in MARGIN, resolved by rescore)
__device__ __forceinline__ void ins4v(float v, int k, float* S, int* I) {
    if (v < S[3]) {
        S[3] = v; I[3] = k;
#pragma unroll
        for (int j = 3; j > 0; --j) {
            if (S[j] < S[j - 1]) {
                float ts = S[j]; S[j] = S[j - 1]; S[j - 1] = ts;
                int   ti = I[j]; I[j] = I[j - 1]; I[j - 1] = ti;
            }
        }
    }
}

// ---------------- kernel 1: MFMA stream GEMM (round-9: epilogue packs flags) -------
// K-loop byte-identical to round 8 (56-60us, VGPR=72, no spill, MfmaUtil 11.4).
// ROUND-9 delta: epilogue writes ONLY packed idxbuf (idx | (flagpos+1)<<10);
// provisional out_idx write dropped — the fused tail kernel produces final idx.
__global__ __launch_bounds__(256, 2) void gemm_swz(
        const float* __restrict__ x, const _Float16* __restrict__ cbs,
        const float* __restrict__ c2,
        int* __restrict__ idxbuf, int* __restrict__ cnt,
        floatx4* __restrict__ flagTop) {
    __shared__ float scr[4][32 * 33];   // SoA [m1|i1|m2|i2][part][px pad33] = 16.9 KB

    const int t = threadIdx.x;
    const int w = t >> 6;
    const int l = t & 63;
    const int l15 = l & 15;
    const int q = l >> 4;
    const int pxg = w >> 1;          // pixel group 0/1 (16 px each)
    const int half = w & 1;          // code half 0/1 (512 codes each)
    const int px0 = blockIdx.x * 32;
    const int bimg = px0 >> 10;      // 32-px blocks never straddle images
    const int hwb = (px0 & 1023) + pxg * 16;
    const float* xb = x + (size_t)bimg * (D_DIM * HW);

    // ---- load A: 16 px x 256 d from fp32 NCHW, convert to f16 frags in regs ----
    half8 A[8];
    {
        float tmp[64];
#pragma unroll
        for (int s = 0; s < 8; ++s)
#pragma unroll
            for (int j = 0; j < 8; ++j)
                tmp[s * 8 + j] = xb[(size_t)(s * 32 + q * 8 + j) * HW + hwb + l15];
#pragma unroll
        for (int s = 0; s < 8; ++s) {
            half8 h;
#pragma unroll
            for (int j = 0; j < 8; ++j) h[j] = (_Float16)tmp[s * 8 + j];
            A[s] = h;
        }
    }

    // ---- stream codes from fragment-ordered buffer: contiguous lane*16B loads ----
    const _Float16* base = cbs + (size_t)half * 131072;   // half block: 32*8*64*8 halves
    half8 B[2][8];
#pragma unroll
    for (int s = 0; s < 8; ++s)
        B[0][s] = *(const half8*)(base + (size_t)s * 512 + l * 8);
    float c2cur = c2[half * 512 + l15];

    float m1[4], m2[4]; int i1[4], i2[4];
#pragma unroll
    for (int a = 0; a < 4; ++a) {
        m1[a] = INFINITY; m2[a] = INFINITY; i1[a] = 0; i2[a] = 0;
    }

#pragma unroll 4
    for (int ch = 0; ch < 32; ++ch) {
        const int cur = ch & 1, nxt = cur ^ 1;
        float c2n = 0.f;
        if (ch < 31) {   // prefetch next chunk while computing this one
            const _Float16* nb = base + (size_t)(ch + 1) * 4096;   // 8*512 halves
#pragma unroll
            for (int s = 0; s < 8; ++s)
                B[nxt][s] = *(const half8*)(nb + (size_t)s * 512 + l * 8);
            c2n = c2[half * 512 + (ch + 1) * 16 + l15];
        }
        // 2 independent MFMA chains (2 K-halves)
        floatx4 ac[2];
        ac[0] = floatx4{0.f, 0.f, 0.f, 0.f};
        ac[1] = floatx4{0.f, 0.f, 0.f, 0.f};
#pragma unroll
        for (int s = 0; s < 4; ++s) {
            ac[0] = __builtin_amdgcn_mfma_f32_16x16x32_f16(A[s],     B[cur][s],     ac[0], 0, 0, 0);
            ac[1] = __builtin_amdgcn_mfma_f32_16x16x32_f16(A[s + 4], B[cur][s + 4], ac[1], 0, 0, 0);
        }
        const int code = half * 512 + ch * 16 + l15;
#pragma unroll
        for (int a = 0; a < 4; ++a) {
            float dot = ac[0][a] + ac[1][a];
            float s = fmaf(-0.001953125f, dot, c2cur);   // c2 - 2*dot (cb scaled 2^10)
            if (s < m1[a]) { m2[a] = m1[a]; i2[a] = i1[a]; m1[a] = s; i1[a] = code; }
            else if (s < m2[a]) { m2[a] = s; i2[a] = code; }
        }
        c2cur = c2n;
    }

    // ---- merge 32 partial top-2s per px (the only barrier in the kernel) ----
    const int part = half * 16 + l15;
#pragma unroll
    for (int a = 0; a < 4; ++a) {
        int px = pxg * 16 + q * 4 + a;
        int o = part * 33 + px;
        scr[0][o] = m1[a];
        scr[1][o] = __int_as_float(i1[a]);
        scr[2][o] = m2[a];
        scr[3][o] = __int_as_float(i2[a]);
    }
    __syncthreads();
    if (t < 32) {
        float S[4] = {INFINITY, INFINITY, INFINITY, INFINITY};
        int   I[4] = {0x7fffffff, 0x7fffffff, 0x7fffffff, 0x7fffffff};
        for (int p = 0; p < 32; ++p) {   // reads: stride 33 -> conflict-free
            int o = p * 33 + t;
            ins4v(scr[0][o], __float_as_int(scr[1][o]), S, I);
            ins4v(scr[2][o], __float_as_int(scr[3][o]), S, I);
        }
        int P = px0 + t;
        int rec = I[0];
        if (S[1] - S[0] <= MARGIN) {     // near-tie: queue for exact reference emulation
            int pos = atomicAdd(cnt, 1);
            if (pos < FLAG_CAP) {
                rec |= (pos + 1) << 10;  // idx in bits 0..9, flag record in 10..23
                flagTop[2 * pos]     = floatx4{S[0], (float)I[0], S[1], (float)I[1]};
                flagTop[2 * pos + 1] = floatx4{S[2], (float)I[2], S[3], (float)I[3]};
            }
        }
        idxbuf[P] = rec;
    }
}

// ---------------- kernel 2 (fused tail): rescore + quantize + loss + finalize -----
// ROUND-9: merges old rescore_wave / quantize_loss_kernel / finalize_loss.
// Rationale: rounds 0-2 consistently show ~88-112us of non-gemm time vs ~35us of
// hand-computed kernel-body floors -> ~10us/dispatch launch+gap overhead dominates.
// 5 dispatches -> 3. Rescore phase is the VERBATIM reference-emulation code
// (numpy-pairwise x2, f64 dots, first-index tiebreak); quantize reads final idx
// from LDS; grid total via last-block-done (agent-scope atomics, G16-safe).
__global__ __launch_bounds__(256) void tail_kernel(
        const float* __restrict__ x, const float* __restrict__ cb,
        const float* __restrict__ c2, const int* __restrict__ idxbuf,
        const floatx4* __restrict__ flagTop, float* __restrict__ out,
        double* __restrict__ partials, int* __restrict__ cd) {
    __shared__ int finIdx[32];
    __shared__ int flgPx[32];
    __shared__ int flgPos[32];
    __shared__ int nflag;
    __shared__ int lastFlag;
    __shared__ double sred[4];

    const int t = threadIdx.x;
    const int px0 = blockIdx.x * 32;

    if (t == 0) nflag = 0;
    __syncthreads();
    if (t < 32) {
        int v = idxbuf[px0 + t];
        finIdx[t] = v & 1023;
        int pos1 = v >> 10;
        if (pos1 > 0) {
            int m = atomicAdd(&nflag, 1);
            flgPx[m] = t; flgPos[m] = pos1 - 1;
        }
    }
    __syncthreads();

    // ---- phase B: rescore flagged pixels, wave-per-entry (verbatim emulation) ----
    const int wv = t >> 6, l = t & 63;
    const int nf = nflag;
    for (int m = wv; m < nf; m += 4) {
        const int pxl_ = flgPx[m];
        const int pos  = flgPos[m];
        const int P = px0 + pxl_;
        floatx4 ta = flagTop[2 * pos], tb = flagTop[2 * pos + 1];
        float s1 = ta[0];
        float cs[4] = {ta[0], ta[2], tb[0], tb[2]};
        int   ck[4] = {(int)ta[1], (int)ta[3], (int)tb[1], (int)tb[3]};
        int nc = 1;
        while (nc < 4 && cs[nc] - s1 <= MARGIN) ++nc;

        const float* xcol = x + (size_t)(P >> 10) * D_DIM * HW + (P & 1023);

        // x2 with numpy's exact pairwise order: lanes 0..15 run the 8-acc chains
        float rj = 0.f;
        if (l < 16) {
            int h = l >> 3, j = l & 7;
            const float* p = xcol + (size_t)(h * 128) * HW;
            float v0 = p[(size_t)j * HW];
            rj = __fmul_rn(v0, v0);
            for (int ii = 1; ii < 16; ++ii) {
                float v = p[(size_t)(ii * 8 + j) * HW];
                rj = __fadd_rn(rj, __fmul_rn(v, v));
            }
        }
        float r0 = __shfl(rj, 0), r1 = __shfl(rj, 1), r2 = __shfl(rj, 2), r3 = __shfl(rj, 3);
        float r4 = __shfl(rj, 4), r5 = __shfl(rj, 5), r6 = __shfl(rj, 6), r7 = __shfl(rj, 7);
        float h0 = __fadd_rn(__fadd_rn(__fadd_rn(r0, r1), __fadd_rn(r2, r3)),
                             __fadd_rn(__fadd_rn(r4, r5), __fadd_rn(r6, r7)));
        r0 = __shfl(rj, 8); r1 = __shfl(rj, 9); r2 = __shfl(rj, 10); r3 = __shfl(rj, 11);
        r4 = __shfl(rj, 12); r5 = __shfl(rj, 13); r6 = __shfl(rj, 14); r7 = __shfl(rj, 15);
        float h1 = __fadd_rn(__fadd_rn(__fadd_rn(r0, r1), __fadd_rn(r2, r3)),
                             __fadd_rn(__fadd_rn(r4, r5), __fadd_rn(r6, r7)));
        float x2 = __fadd_rn(h0, h1);

        // f64 dots: lane covers d = l, l+64, l+128, l+192
        float xv[4];
#pragma unroll
        for (int u = 0; u < 4; ++u) xv[u] = xcol[(size_t)(l + u * 64) * HW];
        double accd[4] = {0.0, 0.0, 0.0, 0.0};
        for (int jc = 0; jc < nc; ++jc) {
            const float* cr = cb + (size_t)ck[jc] * D_DIM;
            double a = 0.0;
#pragma unroll
            for (int u = 0; u < 4; ++u) a += (double)xv[u] * (double)cr[l + u * 64];
#pragma unroll
            for (int off = 32; off > 0; off >>= 1) a += __shfl_down(a, off);
            accd[jc] = a;
        }
        if (l == 0) {
            float bd = INFINITY; int bi = 0x7fffffff;
            for (int jc = 0; jc < nc; ++jc) {
                float mm = (float)accd[jc];
                float t1 = __fsub_rn(x2, __fmul_rn(2.0f, mm));
                float Dq = __fadd_rn(t1, c2[ck[jc]]);
                if (Dq < bd || (Dq == bd && ck[jc] < bi)) { bd = Dq; bi = ck[jc]; }
            }
            finIdx[pxl_] = bi;
        }
    }
    __syncthreads();

    // ---- final idx output ----
    if (t < 32) out[OFF_IDX + px0 + t] = (float)finIdx[t];

    // ---- phase C: quantize + loss partial (verbatim kernel-3 body) ----
    const int pxl = t & 31;
    const int dg = t >> 5;           // d-group: 32 d each
    const int P = px0 + pxl;
    const int bimg = P >> 10, hw = P & 1023;
    const float* xb = x + (size_t)bimg * D_DIM * HW + hw;
    float* qb = out + (size_t)bimg * D_DIM * HW + hw;
    const floatx4* crow = (const floatx4*)(cb + (size_t)finIdx[pxl] * D_DIM) + dg * 8;
    float lsum = 0.f;
#pragma unroll
    for (int i = 0; i < 8; ++i) {
        floatx4 cv = crow[i];
        int dbase = dg * 32 + i * 4;
#pragma unroll
        for (int j = 0; j < 4; ++j) {
            size_t off = (size_t)(dbase + j) * HW;
            float xv = xb[off];
            qb[off] = cv[j];                 // coalesced across pxl lanes
            float df = cv[j] - xv;
            lsum = fmaf(df, df, lsum);
        }
    }
    double ds = (double)lsum;
#pragma unroll
    for (int off = 32; off > 0; off >>= 1) ds += __shfl_down(ds, off);
    if ((t & 63) == 0) sred[t >> 6] = ds;
    __syncthreads();

    // ---- phase D: partial store + last-block grid total (agent-scope atomics) ----
    if (t == 0) {
        double tot = sred[0] + sred[1] + sred[2] + sred[3];
        __hip_atomic_store(&partials[blockIdx.x], tot,
                           __ATOMIC_RELAXED, __HIP_MEMORY_SCOPE_AGENT);
        int prev = __hip_atomic_fetch_add(&cd[1], 1,
                                          __ATOMIC_ACQ_REL, __HIP_MEMORY_SCOPE_AGENT);
        lastFlag = (prev == 1023);
    }
    __syncthreads();
    if (lastFlag) {
        double s = 0.0;
        for (int i = t; i < 1024; i += 256)
            s += __hip_atomic_load(&partials[i], __ATOMIC_RELAXED, __HIP_MEMORY_SCOPE_AGENT);
#pragma unroll
        for (int off = 32; off > 0; off >>= 1) s += __shfl_down(s, off);
        if ((t & 63) == 0) sred[t >> 6] = s;
        __syncthreads();
        if (t == 0) {
            double m = (sred[0] + sred[1] + sred[2] + sred[3]) / (double)NELEM;
            out[OFF_QLOSS] = (float)m;
            out[OFF_ELOSS] = (float)m;            // numerically identical to q_loss
            out[OFF_VQ]    = (float)(1.25 * m);   // q + 0.25*e
        }
    }
}

extern "C" void kernel_launch(void* const* d_in, const int* in_sizes, int n_in,
                              void* d_out, int out_size, void* d_ws, size_t ws_size,
                              hipStream_t stream) {
    const float* x  = (const float*)d_in[0];   // (32,256,32,32)
    const float* cb = (const float*)d_in[1];   // (1024,256)
    float* out = (float*)d_out;
    char* ws = (char*)d_ws;

    int*      idxbuf  = (int*)(ws + WS_IDX);
    float*    c2      = (float*)(ws + WS_C2);
    int*      cd      = (int*)(ws + WS_CNT);     // [0]=flag cnt, [1]=done cnt
    double*   partials= (double*)(ws + WS_PART);
    floatx4*  flagTop = (floatx4*)(ws + WS_FLAGTOP);
    _Float16* cbs     = (_Float16*)(ws + WS_CBS);

    prep_kernel<<<260, 256, 0, stream>>>(cb, cbs, c2, cd);
    gemm_swz<<<NPIX / 32, 256, 0, stream>>>(x, cbs, c2, idxbuf, cd, flagTop);
    tail_kernel<<<NPIX / 32, 256, 0, stream>>>(x, cb, c2, idxbuf, flagTop,
                                               out, partials, cd);
}

// Round 4
// 189.851 us; speedup vs baseline: 1.0404x; 1.0404x over previous
//
#include <hip/hip_runtime.h>
#include <cstdint>

typedef float floatx4 __attribute__((ext_vector_type(4)));
typedef _Float16 half8 __attribute__((ext_vector_type(8)));
typedef _Float16 half4v __attribute__((ext_vector_type(4)));

#define D_DIM 256
#define HW 1024
#define K_CODES 1024
#define NPIX 32768          // B*H*W
#define NELEM 8388608       // B*D*H*W

// output layout (floats): [quantized 8388608][q_loss][e_loss][vq_loss][idx 32768]
#define OFF_QLOSS 8388608
#define OFF_ELOSS 8388609
#define OFF_VQ    8388610
#define OFF_IDX   8388611

// ws layout (bytes) — total ~0.94 MB
#define WS_IDX     0         // int * 32768 = 131072 (packed: idx | (flagpos+1)<<10)
#define WS_C2      131072    // float * 1024 = 4096
#define WS_CNT     135168    // int cnt, int done (+pad) = 64
#define WS_PART    135232    // double * 1024 = 8192
#define WS_FLAGPX  143424    // (unused, kept for layout stability)
#define WS_FLAGTOP 176192    // floatx4 * 2 * 8192 = 262144
#define WS_CBS     438336    // swizzled fp16 codebook = 524288
#define FLAG_CAP   8192

// ref fp32 window 6.1e-5 + fp16 GEMM err ~6e-5, with slack (round-4-proven value)
#define MARGIN 2.5e-4f

// ---- numpy pairwise sum emulation for sum(v*v) over 256 elements ----
__device__ __forceinline__ float np_pairwise_sq_256(const float* __restrict__ a, int stride) {
    float half[2];
#pragma unroll
    for (int h = 0; h < 2; ++h) {
        const float* p = a + (size_t)(h * 128) * stride;
        float r[8];
#pragma unroll
        for (int j = 0; j < 8; ++j) { float t = p[(size_t)j * stride]; r[j] = __fmul_rn(t, t); }
        for (int i = 8; i < 128; i += 8)
#pragma unroll
            for (int j = 0; j < 8; ++j) {
                float t = p[(size_t)(i + j) * stride];
                r[j] = __fadd_rn(r[j], __fmul_rn(t, t));
            }
        half[h] = __fadd_rn(__fadd_rn(__fadd_rn(r[0], r[1]), __fadd_rn(r[2], r[3])),
                            __fadd_rn(__fadd_rn(r[4], r[5]), __fadd_rn(r[6], r[7])));
    }
    return __fadd_rn(half[0], half[1]);
}

// ---------------- kernel 0: prep ----------------
// blocks 0..255: swizzle codebook into MFMA-fragment order (scaled x1024).
// blocks 256..259: c2 (numpy-pairwise exact); b==256,t==0 zeroes cnt+done.
__global__ __launch_bounds__(256) void prep_kernel(const float* __restrict__ cb,
                                                   _Float16* __restrict__ cbs,
                                                   float* __restrict__ c2,
                                                   int* __restrict__ cnt) {
    int b = blockIdx.x;
    if (b < 256) {
        int idx = b * 256 + threadIdx.x;   // (code, d-quad)
        int c = idx >> 6;
        int d = (idx & 63) * 4;
        int s = d >> 5, q = (d >> 3) & 3, j0 = d & 7;
        int half = c >> 9, ch = (c >> 4) & 31, l15 = c & 15;
        int lane = q * 16 + l15;
        size_t o = ((((size_t)(half * 32 + ch) * 8 + s) * 64 + lane) * 8 + j0);
        floatx4 v = *(const floatx4*)(cb + (size_t)c * D_DIM + d);
        half4v h;
#pragma unroll
        for (int j = 0; j < 4; ++j) h[j] = (_Float16)(v[j] * 1024.0f);  // exact pow2
        *(half4v*)(cbs + o) = h;
    } else {
        if (b == 256 && threadIdx.x == 0) { cnt[0] = 0; cnt[1] = 0; }
        int k = (b - 256) * 256 + threadIdx.x;
        c2[k] = np_pairwise_sq_256(cb + (size_t)k * D_DIM, 1);
    }
}

// top-4 insert, no index tiebreak (ties land in MARGIN, resolved by rescore)
__device__ __forceinline__ void ins4v(float v, int k, float* S, int* I) {
    if (v < S[3]) {
        S[3] = v; I[3] = k;
#pragma unroll
        for (int j = 3; j > 0; --j) {
            if (S[j] < S[j - 1]) {
                float ts = S[j]; S[j] = S[j - 1]; S[j - 1] = ts;
                int   ti = I[j]; I[j] = I[j - 1]; I[j - 1] = ti;
            }
        }
    }
}

// ---------------- kernel 1: MFMA stream GEMM (byte-identical to round 9) -------
__global__ __launch_bounds__(256, 2) void gemm_swz(
        const float* __restrict__ x, const _Float16* __restrict__ cbs,
        const float* __restrict__ c2,
        int* __restrict__ idxbuf, int* __restrict__ cnt,
        floatx4* __restrict__ flagTop) {
    __shared__ float scr[4][32 * 33];   // SoA [m1|i1|m2|i2][part][px pad33] = 16.9 KB

    const int t = threadIdx.x;
    const int w = t >> 6;
    const int l = t & 63;
    const int l15 = l & 15;
    const int q = l >> 4;
    const int pxg = w >> 1;          // pixel group 0/1 (16 px each)
    const int half = w & 1;          // code half 0/1 (512 codes each)
    const int px0 = blockIdx.x * 32;
    const int bimg = px0 >> 10;      // 32-px blocks never straddle images
    const int hwb = (px0 & 1023) + pxg * 16;
    const float* xb = x + (size_t)bimg * (D_DIM * HW);

    // ---- load A: 16 px x 256 d from fp32 NCHW, convert to f16 frags in regs ----
    half8 A[8];
    {
        float tmp[64];
#pragma unroll
        for (int s = 0; s < 8; ++s)
#pragma unroll
            for (int j = 0; j < 8; ++j)
                tmp[s * 8 + j] = xb[(size_t)(s * 32 + q * 8 + j) * HW + hwb + l15];
#pragma unroll
        for (int s = 0; s < 8; ++s) {
            half8 h;
#pragma unroll
            for (int j = 0; j < 8; ++j) h[j] = (_Float16)tmp[s * 8 + j];
            A[s] = h;
        }
    }

    // ---- stream codes from fragment-ordered buffer: contiguous lane*16B loads ----
    const _Float16* base = cbs + (size_t)half * 131072;   // half block: 32*8*64*8 halves
    half8 B[2][8];
#pragma unroll
    for (int s = 0; s < 8; ++s)
        B[0][s] = *(const half8*)(base + (size_t)s * 512 + l * 8);
    float c2cur = c2[half * 512 + l15];

    float m1[4], m2[4]; int i1[4], i2[4];
#pragma unroll
    for (int a = 0; a < 4; ++a) {
        m1[a] = INFINITY; m2[a] = INFINITY; i1[a] = 0; i2[a] = 0;
    }

#pragma unroll 4
    for (int ch = 0; ch < 32; ++ch) {
        const int cur = ch & 1, nxt = cur ^ 1;
        float c2n = 0.f;
        if (ch < 31) {   // prefetch next chunk while computing this one
            const _Float16* nb = base + (size_t)(ch + 1) * 4096;   // 8*512 halves
#pragma unroll
            for (int s = 0; s < 8; ++s)
                B[nxt][s] = *(const half8*)(nb + (size_t)s * 512 + l * 8);
            c2n = c2[half * 512 + (ch + 1) * 16 + l15];
        }
        // 2 independent MFMA chains (2 K-halves)
        floatx4 ac[2];
        ac[0] = floatx4{0.f, 0.f, 0.f, 0.f};
        ac[1] = floatx4{0.f, 0.f, 0.f, 0.f};
#pragma unroll
        for (int s = 0; s < 4; ++s) {
            ac[0] = __builtin_amdgcn_mfma_f32_16x16x32_f16(A[s],     B[cur][s],     ac[0], 0, 0, 0);
            ac[1] = __builtin_amdgcn_mfma_f32_16x16x32_f16(A[s + 4], B[cur][s + 4], ac[1], 0, 0, 0);
        }
        const int code = half * 512 + ch * 16 + l15;
#pragma unroll
        for (int a = 0; a < 4; ++a) {
            float dot = ac[0][a] + ac[1][a];
            float s = fmaf(-0.001953125f, dot, c2cur);   // c2 - 2*dot (cb scaled 2^10)
            if (s < m1[a]) { m2[a] = m1[a]; i2[a] = i1[a]; m1[a] = s; i1[a] = code; }
            else if (s < m2[a]) { m2[a] = s; i2[a] = code; }
        }
        c2cur = c2n;
    }

    // ---- merge 32 partial top-2s per px (the only barrier in the kernel) ----
    const int part = half * 16 + l15;
#pragma unroll
    for (int a = 0; a < 4; ++a) {
        int px = pxg * 16 + q * 4 + a;
        int o = part * 33 + px;
        scr[0][o] = m1[a];
        scr[1][o] = __int_as_float(i1[a]);
        scr[2][o] = m2[a];
        scr[3][o] = __int_as_float(i2[a]);
    }
    __syncthreads();
    if (t < 32) {
        float S[4] = {INFINITY, INFINITY, INFINITY, INFINITY};
        int   I[4] = {0x7fffffff, 0x7fffffff, 0x7fffffff, 0x7fffffff};
        for (int p = 0; p < 32; ++p) {   // reads: stride 33 -> conflict-free
            int o = p * 33 + t;
            ins4v(scr[0][o], __float_as_int(scr[1][o]), S, I);
            ins4v(scr[2][o], __float_as_int(scr[3][o]), S, I);
        }
        int P = px0 + t;
        int rec = I[0];
        if (S[1] - S[0] <= MARGIN) {     // near-tie: queue for exact reference emulation
            int pos = atomicAdd(cnt, 1);
            if (pos < FLAG_CAP) {
                rec |= (pos + 1) << 10;  // idx in bits 0..9, flag record in 10..23
                flagTop[2 * pos]     = floatx4{S[0], (float)I[0], S[1], (float)I[1]};
                flagTop[2 * pos + 1] = floatx4{S[2], (float)I[2], S[3], (float)I[3]};
            }
        }
        idxbuf[P] = rec;
    }
}

// ---------------- kernel 2 (fused tail): rescore + quantize + loss + finalize -----
// ROUND-10 delta vs round 9: phase C vectorized. Round-9 counters: tail = 64.5us,
// 64.6 MB at ~1 TB/s, VALUBusy 3.1% -> VMEM-instruction/latency-bound on scalar
// 4B loads+stores (G13). Fix: float4 along the px (hw) dimension for x-load and
// q-store (1 KB/wave-instr); codebook gather solved by staging the block's 32
// final cb rows into LDS (float4-coalesced reads, XOR-quad swizzle d^(px>>2)
// making the transposed read phase ~2-way conflict = free). Per-thread VMEM
// instrs 72 -> 24. Phases A/B/D byte-identical to round 9.
__global__ __launch_bounds__(256) void tail_kernel(
        const float* __restrict__ x, const float* __restrict__ cb,
        const float* __restrict__ c2, const int* __restrict__ idxbuf,
        const floatx4* __restrict__ flagTop, float* __restrict__ out,
        double* __restrict__ partials, int* __restrict__ cd) {
    __shared__ float cbrow[32 * 256];   // 32 KB: row p at [p*256 + (d ^ ((p>>2)&7))]
    __shared__ int finIdx[32];
    __shared__ int flgPx[32];
    __shared__ int flgPos[32];
    __shared__ int nflag;
    __shared__ int lastFlag;
    __shared__ double sred[4];

    const int t = threadIdx.x;
    const int px0 = blockIdx.x * 32;

    if (t == 0) nflag = 0;
    __syncthreads();
    if (t < 32) {
        int v = idxbuf[px0 + t];
        finIdx[t] = v & 1023;
        int pos1 = v >> 10;
        if (pos1 > 0) {
            int m = atomicAdd(&nflag, 1);
            flgPx[m] = t; flgPos[m] = pos1 - 1;
        }
    }
    __syncthreads();

    // ---- phase B: rescore flagged pixels, wave-per-entry (verbatim emulation) ----
    const int wv = t >> 6, l = t & 63;
    const int nf = nflag;
    for (int m = wv; m < nf; m += 4) {
        const int pxl_ = flgPx[m];
        const int pos  = flgPos[m];
        const int P = px0 + pxl_;
        floatx4 ta = flagTop[2 * pos], tb = flagTop[2 * pos + 1];
        float s1 = ta[0];
        float cs[4] = {ta[0], ta[2], tb[0], tb[2]};
        int   ck[4] = {(int)ta[1], (int)ta[3], (int)tb[1], (int)tb[3]};
        int nc = 1;
        while (nc < 4 && cs[nc] - s1 <= MARGIN) ++nc;

        const float* xcol = x + (size_t)(P >> 10) * D_DIM * HW + (P & 1023);

        // x2 with numpy's exact pairwise order: lanes 0..15 run the 8-acc chains
        float rj = 0.f;
        if (l < 16) {
            int h = l >> 3, j = l & 7;
            const float* p = xcol + (size_t)(h * 128) * HW;
            float v0 = p[(size_t)j * HW];
            rj = __fmul_rn(v0, v0);
            for (int ii = 1; ii < 16; ++ii) {
                float v = p[(size_t)(ii * 8 + j) * HW];
                rj = __fadd_rn(rj, __fmul_rn(v, v));
            }
        }
        float r0 = __shfl(rj, 0), r1 = __shfl(rj, 1), r2 = __shfl(rj, 2), r3 = __shfl(rj, 3);
        float r4 = __shfl(rj, 4), r5 = __shfl(rj, 5), r6 = __shfl(rj, 6), r7 = __shfl(rj, 7);
        float h0 = __fadd_rn(__fadd_rn(__fadd_rn(r0, r1), __fadd_rn(r2, r3)),
                             __fadd_rn(__fadd_rn(r4, r5), __fadd_rn(r6, r7)));
        r0 = __shfl(rj, 8); r1 = __shfl(rj, 9); r2 = __shfl(rj, 10); r3 = __shfl(rj, 11);
        r4 = __shfl(rj, 12); r5 = __shfl(rj, 13); r6 = __shfl(rj, 14); r7 = __shfl(rj, 15);
        float h1 = __fadd_rn(__fadd_rn(__fadd_rn(r0, r1), __fadd_rn(r2, r3)),
                             __fadd_rn(__fadd_rn(r4, r5), __fadd_rn(r6, r7)));
        float x2 = __fadd_rn(h0, h1);

        // f64 dots: lane covers d = l, l+64, l+128, l+192
        float xv[4];
#pragma unroll
        for (int u = 0; u < 4; ++u) xv[u] = xcol[(size_t)(l + u * 64) * HW];
        double accd[4] = {0.0, 0.0, 0.0, 0.0};
        for (int jc = 0; jc < nc; ++jc) {
            const float* cr = cb + (size_t)ck[jc] * D_DIM;
            double a = 0.0;
#pragma unroll
            for (int u = 0; u < 4; ++u) a += (double)xv[u] * (double)cr[l + u * 64];
#pragma unroll
            for (int off = 32; off > 0; off >>= 1) a += __shfl_down(a, off);
            accd[jc] = a;
        }
        if (l == 0) {
            float bd = INFINITY; int bi = 0x7fffffff;
            for (int jc = 0; jc < nc; ++jc) {
                float mm = (float)accd[jc];
                float t1 = __fsub_rn(x2, __fmul_rn(2.0f, mm));
                float Dq = __fadd_rn(t1, c2[ck[jc]]);
                if (Dq < bd || (Dq == bd && ck[jc] < bi)) { bd = Dq; bi = ck[jc]; }
            }
            finIdx[pxl_] = bi;
        }
    }
    __syncthreads();

    // ---- final idx output ----
    if (t < 32) out[OFF_IDX + px0 + t] = (float)finIdx[t];

    // ---- phase C1: stage the 32 final cb rows into LDS (float4-coalesced) ----
    // thread t covers rows p = pp*4 + (t>>6), d-quad = (t&63)*4; XOR-quad swizzle
    {
        const int wq = t >> 6;       // 0..3
        const int dl = t & 63;       // d-quad index
#pragma unroll
        for (int pp = 0; pp < 8; ++pp) {
            int p = pp * 4 + wq;
            floatx4 v = *(const floatx4*)(cb + (size_t)finIdx[p] * D_DIM + dl * 4);
            int q8 = pp;             // (p>>2)&7 == pp since wq < 4
#pragma unroll
            for (int jj = 0; jj < 4; ++jj)
                cbrow[p * 256 + ((dl * 4 + jj) ^ q8)] = v[jj];
        }
    }
    __syncthreads();

    // ---- phase C2: quantize + loss, float4 along px ----
    // thread t: px-quad = t&7 (4 px), d-group = t>>3 (8 d); per j: 1 float4 x load,
    // 4 LDS reads (~2-way, free), 1 float4 q store -> 1 KB/wave-instruction.
    const int quad = t & 7;
    const int dg = t >> 3;
    const int bimg = px0 >> 10, hw0 = px0 & 1023;
    const float* xb = x + (size_t)bimg * D_DIM * HW + hw0 + quad * 4;
    float* qb = out + (size_t)bimg * D_DIM * HW + hw0 + quad * 4;
    float lsum = 0.f;
#pragma unroll
    for (int j = 0; j < 8; ++j) {
        int d = dg * 8 + j;
        size_t off = (size_t)d * HW;
        floatx4 xv = *(const floatx4*)(xb + off);
        floatx4 cv;
#pragma unroll
        for (int k = 0; k < 4; ++k)
            cv[k] = cbrow[(quad * 4 + k) * 256 + (d ^ quad)];
        *(floatx4*)(qb + off) = cv;
#pragma unroll
        for (int k = 0; k < 4; ++k) {
            float df = cv[k] - xv[k];
            lsum = fmaf(df, df, lsum);
        }
    }
    double ds = (double)lsum;
#pragma unroll
    for (int off = 32; off > 0; off >>= 1) ds += __shfl_down(ds, off);
    if ((t & 63) == 0) sred[t >> 6] = ds;
    __syncthreads();

    // ---- phase D: partial store + last-block grid total (agent-scope atomics) ----
    if (t == 0) {
        double tot = sred[0] + sred[1] + sred[2] + sred[3];
        __hip_atomic_store(&partials[blockIdx.x], tot,
                           __ATOMIC_RELAXED, __HIP_MEMORY_SCOPE_AGENT);
        int prev = __hip_atomic_fetch_add(&cd[1], 1,
                                          __ATOMIC_ACQ_REL, __HIP_MEMORY_SCOPE_AGENT);
        lastFlag = (prev == 1023);
    }
    __syncthreads();
    if (lastFlag) {
        double s = 0.0;
        for (int i = t; i < 1024; i += 256)
            s += __hip_atomic_load(&partials[i], __ATOMIC_RELAXED, __HIP_MEMORY_SCOPE_AGENT);
#pragma unroll
        for (int off = 32; off > 0; off >>= 1) s += __shfl_down(s, off);
        if ((t & 63) == 0) sred[t >> 6] = s;
        __syncthreads();
        if (t == 0) {
            double m = (sred[0] + sred[1] + sred[2] + sred[3]) / (double)NELEM;
            out[OFF_QLOSS] = (float)m;
            out[OFF_ELOSS] = (float)m;            // numerically identical to q_loss
            out[OFF_VQ]    = (float)(1.25 * m);   // q + 0.25*e
        }
    }
}

extern "C" void kernel_launch(void* const* d_in, const int* in_sizes, int n_in,
                              void* d_out, int out_size, void* d_ws, size_t ws_size,
                              hipStream_t stream) {
    const float* x  = (const float*)d_in[0];   // (32,256,32,32)
    const float* cb = (const float*)d_in[1];   // (1024,256)
    float* out = (float*)d_out;
    char* ws = (char*)d_ws;

    int*      idxbuf  = (int*)(ws + WS_IDX);
    float*    c2      = (float*)(ws + WS_C2);
    int*      cd      = (int*)(ws + WS_CNT);     // [0]=flag cnt, [1]=done cnt
    double*   partials= (double*)(ws + WS_PART);
    floatx4*  flagTop = (floatx4*)(ws + WS_FLAGTOP);
    _Float16* cbs     = (_Float16*)(ws + WS_CBS);

    prep_kernel<<<260, 256, 0, stream>>>(cb, cbs, c2, cd);
    gemm_swz<<<NPIX / 32, 256, 0, stream>>>(x, cbs, c2, idxbuf, cd, flagTop);
    tail_kernel<<<NPIX / 32, 256, 0, stream>>>(x, cb, c2, idxbuf, flagTop,
                                               out, partials, cd);
}